// Round 4
// baseline (99.655 us; speedup 1.0000x reference)
//
#include <hip/hip_runtime.h>
#include <math.h>

#define HW     224
#define OW     223
#define FLAT   (OW * OW)        // 49729
#define NB     1024             // batch
#define NGRP   (OW * 56)        // 12488 groups of 4 positions (56 col-groups/row)
#define EWPK   (NGRP * 16)      // packed embed_w floats = 199808
#define NSPLIT 2
#define GPB    (NGRP / NSPLIT)  // 6244 groups per block
#define FULLIT (GPB / 256)      // 24 full iterations
#define TAILN  (GPB - FULLIT * 256)  // 100 active threads in tail

// ---------------------------------------------------------------------------
// Kernel 0: repack embed_w [4][FLAT] -> ew_pack[g][c][4], g = i*56 + j0/4,
// zero-filled where j0+l >= 223 (i.e. the .w slot of the jg==55 group).
// ---------------------------------------------------------------------------
__global__ __launch_bounds__(256) void pack_ew_kernel(
    const float* __restrict__ embed_w, float* __restrict__ ew_pack)
{
    int idx = blockIdx.x * 256 + threadIdx.x;      // one (g, c) pair
    if (idx >= NGRP * 4) return;
    int g = idx >> 2;
    int c = idx & 3;
    int i  = g / 56;
    int j0 = (g - i * 56) * 4;
    const float* src = embed_w + (size_t)c * FLAT + (size_t)i * OW + j0;
    float v0 = src[0];
    float v1 = (j0 + 1 < OW) ? src[1] : 0.f;
    float v2 = (j0 + 2 < OW) ? src[2] : 0.f;
    float v3 = (j0 + 3 < OW) ? src[3] : 0.f;
    ((float4*)(ew_pack + (size_t)g * 16 + c * 4))[0] = make_float4(v0, v1, v2, v3);
}

// ---------------------------------------------------------------------------
// Kernel 1: fused conv2d(k=2) + sigmoid + embed projection.
// 2 blocks per image (groups [0,6244) and [6244,12488)); branch-free body.
// Edge group jg==55: its 4th position (col 223) is invalid; ew_pack .w = 0
// there, so te/be may hold any in-bounds value. te = xr[4] is always inside
// the image; be's offset is clamped HW+4 -> HW at the edge so it never
// crosses the end of the x allocation (b=1023, i=222 case).
// ---------------------------------------------------------------------------
__global__ __launch_bounds__(256, 6) void conv_embed_part(
    const float* __restrict__ x, const float* __restrict__ conv_w,
    const float* __restrict__ conv_b, const float* __restrict__ ew_pack,
    float* __restrict__ partial)   // [NSPLIT][NB][4]
{
    const int blk  = blockIdx.x;
    const int b    = blk >> 1;
    const int part = blk & 1;
    const int tid  = threadIdx.x;
    const int base = part * GPB;

    const float w00 = conv_w[0], w01 = conv_w[1];
    const float w10 = conv_w[2], w11 = conv_w[3];
    const float cb  = conv_b[0];

    const float* __restrict__ xb = x + (size_t)b * (HW * HW);

    float a0 = 0.f, a1 = 0.f, a2 = 0.f, a3 = 0.f;

    #pragma unroll 4
    for (int it = 0; it < FULLIT; ++it) {
        const int g  = base + it * 256 + tid;
        const int i  = g / 56;
        const int jg = g - i * 56;
        const float* xr = xb + i * HW + jg * 4;
        float4 t  = *(const float4*)xr;
        float  te = xr[4];
        float4 bt = *(const float4*)(xr + HW);
        float  be = xr[(jg == 55) ? HW : HW + 4];
        const float4* ep = (const float4*)(ew_pack + (size_t)g * 16);
        float4 e0 = ep[0], e1 = ep[1], e2 = ep[2], e3 = ep[3];

        float z0 = w00 * t.x + w01 * t.y + w10 * bt.x + w11 * bt.y + cb;
        float z1 = w00 * t.y + w01 * t.z + w10 * bt.y + w11 * bt.z + cb;
        float z2 = w00 * t.z + w01 * t.w + w10 * bt.z + w11 * bt.w + cb;
        float z3 = w00 * t.w + w01 * te  + w10 * bt.w + w11 * be  + cb;
        float s0 = __builtin_amdgcn_rcpf(1.0f + __expf(-z0));
        float s1 = __builtin_amdgcn_rcpf(1.0f + __expf(-z1));
        float s2 = __builtin_amdgcn_rcpf(1.0f + __expf(-z2));
        float s3 = __builtin_amdgcn_rcpf(1.0f + __expf(-z3));

        a0 += s0 * e0.x + s1 * e0.y + s2 * e0.z + s3 * e0.w;
        a1 += s0 * e1.x + s1 * e1.y + s2 * e1.z + s3 * e1.w;
        a2 += s0 * e2.x + s1 * e2.y + s2 * e2.z + s3 * e2.w;
        a3 += s0 * e3.x + s1 * e3.y + s2 * e3.z + s3 * e3.w;
    }
    if (tid < TAILN) {   // tail: last 100 groups of this block's range
        const int g  = base + FULLIT * 256 + tid;
        const int i  = g / 56;
        const int jg = g - i * 56;
        const float* xr = xb + i * HW + jg * 4;
        float4 t  = *(const float4*)xr;
        float  te = xr[4];
        float4 bt = *(const float4*)(xr + HW);
        float  be = xr[(jg == 55) ? HW : HW + 4];
        const float4* ep = (const float4*)(ew_pack + (size_t)g * 16);
        float4 e0 = ep[0], e1 = ep[1], e2 = ep[2], e3 = ep[3];
        float z0 = w00 * t.x + w01 * t.y + w10 * bt.x + w11 * bt.y + cb;
        float z1 = w00 * t.y + w01 * t.z + w10 * bt.y + w11 * bt.z + cb;
        float z2 = w00 * t.z + w01 * t.w + w10 * bt.z + w11 * bt.w + cb;
        float z3 = w00 * t.w + w01 * te  + w10 * bt.w + w11 * be  + cb;
        float s0 = __builtin_amdgcn_rcpf(1.0f + __expf(-z0));
        float s1 = __builtin_amdgcn_rcpf(1.0f + __expf(-z1));
        float s2 = __builtin_amdgcn_rcpf(1.0f + __expf(-z2));
        float s3 = __builtin_amdgcn_rcpf(1.0f + __expf(-z3));
        a0 += s0 * e0.x + s1 * e0.y + s2 * e0.z + s3 * e0.w;
        a1 += s0 * e1.x + s1 * e1.y + s2 * e1.z + s3 * e1.w;
        a2 += s0 * e2.x + s1 * e2.y + s2 * e2.z + s3 * e2.w;
        a3 += s0 * e3.x + s1 * e3.y + s2 * e3.z + s3 * e3.w;
    }

    // wave (64-lane) reduction
    #pragma unroll
    for (int off = 32; off > 0; off >>= 1) {
        a0 += __shfl_down(a0, off, 64);
        a1 += __shfl_down(a1, off, 64);
        a2 += __shfl_down(a2, off, 64);
        a3 += __shfl_down(a3, off, 64);
    }

    __shared__ float red[4][4];
    const int wid  = tid >> 6;
    const int lane = tid & 63;
    if (lane == 0) {
        red[wid][0] = a0; red[wid][1] = a1; red[wid][2] = a2; red[wid][3] = a3;
    }
    __syncthreads();
    if (tid == 0) {
        float r0 = red[0][0] + red[1][0] + red[2][0] + red[3][0];
        float r1 = red[0][1] + red[1][1] + red[2][1] + red[3][1];
        float r2 = red[0][2] + red[1][2] + red[2][2] + red[3][2];
        float r3 = red[0][3] + red[1][3] + red[2][3] + red[3][3];
        ((float4*)(partial + ((size_t)part * NB + b) * 4))[0] =
            make_float4(r0, r1, r2, r3);
    }
}

// ---------------------------------------------------------------------------
// Fallback (round-1 style, single block per image, writes embedded directly).
// ---------------------------------------------------------------------------
__global__ __launch_bounds__(256) void conv_embed_kernel(
    const float* __restrict__ x, const float* __restrict__ conv_w,
    const float* __restrict__ conv_b, const float* __restrict__ embed_w,
    const float* __restrict__ embed_b, float* __restrict__ embedded)
{
    const int b   = blockIdx.x;
    const int tid = threadIdx.x;
    const float w00 = conv_w[0], w01 = conv_w[1];
    const float w10 = conv_w[2], w11 = conv_w[3];
    const float cb  = conv_b[0];
    const float* __restrict__ xb  = x + (size_t)b * (HW * HW);
    const float* __restrict__ ew0 = embed_w;
    const float* __restrict__ ew1 = embed_w + FLAT;
    const float* __restrict__ ew2 = embed_w + 2 * FLAT;
    const float* __restrict__ ew3 = embed_w + 3 * FLAT;
    float a0 = 0.f, a1 = 0.f, a2 = 0.f, a3 = 0.f;
    for (int p = tid; p < FLAT; p += 256) {
        unsigned up = (unsigned)p;
        unsigned i  = up / 223u;
        unsigned j  = up - i * 223u;
        const float* xr = xb + i * HW + j;
        float z = w00 * xr[0] + w01 * xr[1] + w10 * xr[HW] + w11 * xr[HW + 1] + cb;
        float s = 1.0f / (1.0f + __expf(-z));
        a0 += s * ew0[p]; a1 += s * ew1[p]; a2 += s * ew2[p]; a3 += s * ew3[p];
    }
    #pragma unroll
    for (int off = 32; off > 0; off >>= 1) {
        a0 += __shfl_down(a0, off, 64);
        a1 += __shfl_down(a1, off, 64);
        a2 += __shfl_down(a2, off, 64);
        a3 += __shfl_down(a3, off, 64);
    }
    __shared__ float red[4][4];
    const int wid  = tid >> 6;
    const int lane = tid & 63;
    if (lane == 0) { red[wid][0]=a0; red[wid][1]=a1; red[wid][2]=a2; red[wid][3]=a3; }
    __syncthreads();
    if (tid == 0) {
        float r0 = red[0][0]+red[1][0]+red[2][0]+red[3][0]+embed_b[0];
        float r1 = red[0][1]+red[1][1]+red[2][1]+red[3][1]+embed_b[1];
        float r2 = red[0][2]+red[1][2]+red[2][2]+red[3][2]+embed_b[2];
        float r3 = red[0][3]+red[1][3]+red[2][3]+red[3][3]+embed_b[3];
        ((float4*)(embedded + (size_t)b * 4))[0] = make_float4(r0, r1, r2, r3);
    }
}

// ---------------------------------------------------------------------------
// Kernel 2: sum partials (+bias) -> embedded, then q = e@rot, k = e@ent
// ---------------------------------------------------------------------------
__global__ __launch_bounds__(256) void qk_reduce_kernel(
    const float* __restrict__ partial, const float* __restrict__ embed_b,
    const float* __restrict__ rot, const float* __restrict__ ent,
    float* __restrict__ embedded, float* __restrict__ q, float* __restrict__ k)
{
    int b = blockIdx.x * 256 + threadIdx.x;
    if (b >= NB) return;
    float4 p0 = ((const float4*)partial)[b];
    float4 p1 = ((const float4*)partial)[NB + b];
    float4 ev = make_float4(p0.x + p1.x + embed_b[0],
                            p0.y + p1.y + embed_b[1],
                            p0.z + p1.z + embed_b[2],
                            p0.w + p1.w + embed_b[3]);
    ((float4*)embedded)[b] = ev;
    float qv[4], kv[4];
    #pragma unroll
    for (int c = 0; c < 4; ++c) {
        qv[c] = ev.x * rot[0*4+c] + ev.y * rot[1*4+c] + ev.z * rot[2*4+c] + ev.w * rot[3*4+c];
        kv[c] = ev.x * ent[0*4+c] + ev.y * ent[1*4+c] + ev.z * ent[2*4+c] + ev.w * ent[3*4+c];
    }
    ((float4*)q)[b] = make_float4(qv[0], qv[1], qv[2], qv[3]);
    ((float4*)k)[b] = make_float4(kv[0], kv[1], kv[2], kv[3]);
}

// plain qk for the fallback path
__global__ __launch_bounds__(256) void qk_kernel(
    const float* __restrict__ embedded, const float* __restrict__ rot,
    const float* __restrict__ ent, float* __restrict__ q, float* __restrict__ k)
{
    int b = blockIdx.x * 256 + threadIdx.x;
    if (b >= NB) return;
    float4 ev = ((const float4*)embedded)[b];
    float qv[4], kv[4];
    #pragma unroll
    for (int c = 0; c < 4; ++c) {
        qv[c] = ev.x * rot[0*4+c] + ev.y * rot[1*4+c] + ev.z * rot[2*4+c] + ev.w * rot[3*4+c];
        kv[c] = ev.x * ent[0*4+c] + ev.y * ent[1*4+c] + ev.z * ent[2*4+c] + ev.w * ent[3*4+c];
    }
    ((float4*)q)[b] = make_float4(qv[0], qv[1], qv[2], qv[3]);
    ((float4*)k)[b] = make_float4(kv[0], kv[1], kv[2], kv[3]);
}

// ---------------------------------------------------------------------------
// Kernel 3: per-row softmax attention + mean + sigmoid -> out [NB, 2]
// ---------------------------------------------------------------------------
__global__ __launch_bounds__(256) void attn_kernel(
    const float* __restrict__ embedded, const float* __restrict__ q,
    const float* __restrict__ k, float* __restrict__ out)
{
    __shared__ float4 k_lds[NB];
    __shared__ float4 e_lds[NB];
    const int r   = blockIdx.x;
    const int tid = threadIdx.x;

    for (int c = tid; c < NB; c += 256) {
        k_lds[c] = ((const float4*)k)[c];
        e_lds[c] = ((const float4*)embedded)[c];
    }
    __syncthreads();

    const float4 qr = ((const float4*)q)[r];

    float m = -INFINITY, l = 0.f;
    float a0 = 0.f, a1 = 0.f, a2 = 0.f, a3 = 0.f;

    for (int c = tid; c < NB; c += 256) {
        float4 kc = k_lds[c];
        float s = 0.5f * (qr.x * kc.x + qr.y * kc.y + qr.z * kc.z + qr.w * kc.w);
        float mn    = fmaxf(m, s);
        float scale = __expf(m - mn);
        float p     = __expf(s - mn);
        float4 ec = e_lds[c];
        l  = l  * scale + p;
        a0 = a0 * scale + p * ec.x;
        a1 = a1 * scale + p * ec.y;
        a2 = a2 * scale + p * ec.z;
        a3 = a3 * scale + p * ec.w;
        m = mn;
    }

    #pragma unroll
    for (int off = 32; off > 0; off >>= 1) {
        float m2 = __shfl_down(m,  off, 64);
        float l2 = __shfl_down(l,  off, 64);
        float b0 = __shfl_down(a0, off, 64);
        float b1 = __shfl_down(a1, off, 64);
        float b2 = __shfl_down(a2, off, 64);
        float b3 = __shfl_down(a3, off, 64);
        float mn = fmaxf(m, m2);
        float s1 = __expf(m - mn), s2 = __expf(m2 - mn);
        l  = l  * s1 + l2 * s2;
        a0 = a0 * s1 + b0 * s2;
        a1 = a1 * s1 + b1 * s2;
        a2 = a2 * s1 + b2 * s2;
        a3 = a3 * s1 + b3 * s2;
        m = mn;
    }

    __shared__ float wred[4][6];
    const int wid  = tid >> 6;
    const int lane = tid & 63;
    if (lane == 0) {
        wred[wid][0] = m;  wred[wid][1] = l;
        wred[wid][2] = a0; wred[wid][3] = a1;
        wred[wid][4] = a2; wred[wid][5] = a3;
    }
    __syncthreads();
    if (tid == 0) {
        float M = wred[0][0], L = wred[0][1];
        float A0 = wred[0][2], A1 = wred[0][3], A2 = wred[0][4], A3 = wred[0][5];
        #pragma unroll
        for (int w = 1; w < 4; ++w) {
            float m2 = wred[w][0];
            float mn = fmaxf(M, m2);
            float s1 = __expf(M - mn), s2 = __expf(m2 - mn);
            L  = L  * s1 + wred[w][1] * s2;
            A0 = A0 * s1 + wred[w][2] * s2;
            A1 = A1 * s1 + wred[w][3] * s2;
            A2 = A2 * s1 + wred[w][4] * s2;
            A3 = A3 * s1 + wred[w][5] * s2;
            M = mn;
        }
        float mean = (A0 + A1 + A2 + A3) / (4.0f * L);
        float prob = 1.0f / (1.0f + __expf(-mean));
        out[r * 2 + 0] = prob;
        out[r * 2 + 1] = 1.0f - prob;
    }
}

// ---------------------------------------------------------------------------
extern "C" void kernel_launch(void* const* d_in, const int* in_sizes, int n_in,
                              void* d_out, int out_size, void* d_ws, size_t ws_size,
                              hipStream_t stream) {
    const float* x       = (const float*)d_in[0];
    const float* conv_w  = (const float*)d_in[1];
    const float* conv_b  = (const float*)d_in[2];
    const float* embed_w = (const float*)d_in[3];
    const float* embed_b = (const float*)d_in[4];
    const float* rot     = (const float*)d_in[5];
    const float* ent     = (const float*)d_in[6];
    float* out = (float*)d_out;

    float* partial  = (float*)d_ws;               // NSPLIT*NB*4 floats
    float* embedded = partial + NSPLIT * NB * 4;  // NB*4
    float* q        = embedded + NB * 4;          // NB*4
    float* k        = q + NB * 4;                 // NB*4
    float* ew_pack  = k + NB * 4;                 // EWPK floats

    const size_t need = (size_t)(NSPLIT * NB * 4 + NB * 12 + EWPK) * sizeof(float);

    if (ws_size >= need) {
        pack_ew_kernel<<<(NGRP * 4 + 255) / 256, 256, 0, stream>>>(embed_w, ew_pack);
        conv_embed_part<<<NB * NSPLIT, 256, 0, stream>>>(x, conv_w, conv_b,
                                                         ew_pack, partial);
        qk_reduce_kernel<<<NB / 256, 256, 0, stream>>>(partial, embed_b, rot, ent,
                                                       embedded, q, k);
    } else {
        conv_embed_kernel<<<NB, 256, 0, stream>>>(x, conv_w, conv_b, embed_w,
                                                  embed_b, embedded);
        qk_kernel<<<NB / 256, 256, 0, stream>>>(embedded, rot, ent, q, k);
    }
    attn_kernel<<<NB, 256, 0, stream>>>(embedded, q, k, out);
}

// Round 5
// 76.651 us; speedup vs baseline: 1.3001x; 1.3001x over previous
//
#include <hip/hip_runtime.h>
#include <math.h>

#define HW     224
#define OW     223
#define FLAT   (OW * OW)        // 49729
#define NB     1024             // batch
#define NGRP   (OW * 56)        // 12488 groups of 4 positions (56 col-groups/row)
#define EWPK   (NGRP * 16)      // packed embed_w floats = 199808
#define NCHUNK 49               // ceil(NGRP/256): 48 full + 1 partial (200)
#define NI     4                // images per block
#define NSLICE 8                // position slices
#define ISETS  (NB / NI)        // 256 image sets

// ---------------------------------------------------------------------------
// Kernel 0: repack embed_w [4][FLAT] -> ew_pack[g][c][4], g = i*56 + j0/4,
// zero-filled where j0+l >= 223 (the .w slot of the jg==55 group).
// ---------------------------------------------------------------------------
__global__ __launch_bounds__(256) void pack_ew_kernel(
    const float* __restrict__ embed_w, float* __restrict__ ew_pack)
{
    int idx = blockIdx.x * 256 + threadIdx.x;      // one (g, c) pair
    if (idx >= NGRP * 4) return;
    int g = idx >> 2;
    int c = idx & 3;
    int i  = g / 56;
    int j0 = (g - i * 56) * 4;
    const float* src = embed_w + (size_t)c * FLAT + (size_t)i * OW + j0;
    float v0 = src[0];
    float v1 = (j0 + 1 < OW) ? src[1] : 0.f;
    float v2 = (j0 + 2 < OW) ? src[2] : 0.f;
    float v3 = (j0 + 3 < OW) ? src[3] : 0.f;
    ((float4*)(ew_pack + (size_t)g * 16 + c * 4))[0] = make_float4(v0, v1, v2, v3);
}

// ---------------------------------------------------------------------------
// Kernel 1: fused conv2d(k=2) + sigmoid + embed projection.
// Block = (image set of NI=4, position slice of NSLICE=8). Per chunk, the
// thread issues 4 ew float4 loads + NI x (t,bt float4 + te,be scalar) as one
// independent batch (28 loads in flight), then computes. ew is read once per
// NI images (4x amortization vs round 4).
// Edge group jg==55: position col 223 invalid, ew .w == 0 annihilates it;
// te = xr[4] wraps to next row's col 0 (in-bounds); be offset clamped
// HW+4 -> HW so the last image/row never reads past the allocation.
// ---------------------------------------------------------------------------
__global__ __launch_bounds__(256, 4) void conv_embed_multi(
    const float* __restrict__ x, const float* __restrict__ conv_w,
    const float* __restrict__ conv_b, const float* __restrict__ ew_pack,
    float* __restrict__ partial)   // [NSLICE][NB][4]
{
    const int blk   = blockIdx.x;
    const int slice = blk & (NSLICE - 1);
    const int b0    = (blk >> 3) * NI;
    const int tid   = threadIdx.x;

    const float w00 = conv_w[0], w01 = conv_w[1];
    const float w10 = conv_w[2], w11 = conv_w[3];
    const float cb  = conv_b[0];

    const float* __restrict__ xb0 = x + (size_t)b0 * (HW * HW);

    float acc[NI][4];
    #pragma unroll
    for (int im = 0; im < NI; ++im) {
        acc[im][0] = 0.f; acc[im][1] = 0.f; acc[im][2] = 0.f; acc[im][3] = 0.f;
    }

    for (int c = slice; c < NCHUNK; c += NSLICE) {
        const int g = c * 256 + tid;
        if (g >= NGRP) continue;                 // only the last chunk
        const int i     = g / 56;
        const int jg    = g - i * 56;
        const int xoff  = i * HW + jg * 4;
        const int beoff = (jg == 55) ? HW : HW + 4;

        // ---- load phase: 28 independent loads ----
        const float4* ep = (const float4*)(ew_pack + (size_t)g * 16);
        float4 e0 = ep[0], e1 = ep[1], e2 = ep[2], e3 = ep[3];

        float4 t[NI], bt[NI];
        float  te[NI], be[NI];
        #pragma unroll
        for (int im = 0; im < NI; ++im) {
            const float* xr = xb0 + (size_t)im * (HW * HW) + xoff;
            t[im]  = *(const float4*)xr;
            te[im] = xr[4];
            bt[im] = *(const float4*)(xr + HW);
            be[im] = xr[beoff];
        }

        // ---- compute phase ----
        #pragma unroll
        for (int im = 0; im < NI; ++im) {
            float z0 = w00 * t[im].x + w01 * t[im].y + w10 * bt[im].x + w11 * bt[im].y + cb;
            float z1 = w00 * t[im].y + w01 * t[im].z + w10 * bt[im].y + w11 * bt[im].z + cb;
            float z2 = w00 * t[im].z + w01 * t[im].w + w10 * bt[im].z + w11 * bt[im].w + cb;
            float z3 = w00 * t[im].w + w01 * te[im] + w10 * bt[im].w + w11 * be[im] + cb;
            float s0 = __builtin_amdgcn_rcpf(1.0f + __expf(-z0));
            float s1 = __builtin_amdgcn_rcpf(1.0f + __expf(-z1));
            float s2 = __builtin_amdgcn_rcpf(1.0f + __expf(-z2));
            float s3 = __builtin_amdgcn_rcpf(1.0f + __expf(-z3));
            acc[im][0] += s0 * e0.x + s1 * e0.y + s2 * e0.z + s3 * e0.w;
            acc[im][1] += s0 * e1.x + s1 * e1.y + s2 * e1.z + s3 * e1.w;
            acc[im][2] += s0 * e2.x + s1 * e2.y + s2 * e2.z + s3 * e2.w;
            acc[im][3] += s0 * e3.x + s1 * e3.y + s2 * e3.z + s3 * e3.w;
        }
    }

    // ---- wave (64-lane) butterfly reduction of 16 accumulators ----
    #pragma unroll
    for (int off = 32; off > 0; off >>= 1) {
        #pragma unroll
        for (int im = 0; im < NI; ++im) {
            acc[im][0] += __shfl_down(acc[im][0], off, 64);
            acc[im][1] += __shfl_down(acc[im][1], off, 64);
            acc[im][2] += __shfl_down(acc[im][2], off, 64);
            acc[im][3] += __shfl_down(acc[im][3], off, 64);
        }
    }

    __shared__ float red[4][NI][4];
    const int wid  = tid >> 6;
    const int lane = tid & 63;
    if (lane == 0) {
        #pragma unroll
        for (int im = 0; im < NI; ++im) {
            red[wid][im][0] = acc[im][0]; red[wid][im][1] = acc[im][1];
            red[wid][im][2] = acc[im][2]; red[wid][im][3] = acc[im][3];
        }
    }
    __syncthreads();
    if (tid < NI) {      // thread im writes image b0+im
        float r0 = red[0][tid][0] + red[1][tid][0] + red[2][tid][0] + red[3][tid][0];
        float r1 = red[0][tid][1] + red[1][tid][1] + red[2][tid][1] + red[3][tid][1];
        float r2 = red[0][tid][2] + red[1][tid][2] + red[2][tid][2] + red[3][tid][2];
        float r3 = red[0][tid][3] + red[1][tid][3] + red[2][tid][3] + red[3][tid][3];
        ((float4*)(partial + ((size_t)slice * NB + b0 + tid) * 4))[0] =
            make_float4(r0, r1, r2, r3);
    }
}

// ---------------------------------------------------------------------------
// Fallback (round-1 style, single block per image, writes embedded directly).
// ---------------------------------------------------------------------------
__global__ __launch_bounds__(256) void conv_embed_kernel(
    const float* __restrict__ x, const float* __restrict__ conv_w,
    const float* __restrict__ conv_b, const float* __restrict__ embed_w,
    const float* __restrict__ embed_b, float* __restrict__ embedded)
{
    const int b   = blockIdx.x;
    const int tid = threadIdx.x;
    const float w00 = conv_w[0], w01 = conv_w[1];
    const float w10 = conv_w[2], w11 = conv_w[3];
    const float cb  = conv_b[0];
    const float* __restrict__ xb  = x + (size_t)b * (HW * HW);
    const float* __restrict__ ew0 = embed_w;
    const float* __restrict__ ew1 = embed_w + FLAT;
    const float* __restrict__ ew2 = embed_w + 2 * FLAT;
    const float* __restrict__ ew3 = embed_w + 3 * FLAT;
    float a0 = 0.f, a1 = 0.f, a2 = 0.f, a3 = 0.f;
    for (int p = tid; p < FLAT; p += 256) {
        unsigned up = (unsigned)p;
        unsigned i  = up / 223u;
        unsigned j  = up - i * 223u;
        const float* xr = xb + i * HW + j;
        float z = w00 * xr[0] + w01 * xr[1] + w10 * xr[HW] + w11 * xr[HW + 1] + cb;
        float s = 1.0f / (1.0f + __expf(-z));
        a0 += s * ew0[p]; a1 += s * ew1[p]; a2 += s * ew2[p]; a3 += s * ew3[p];
    }
    #pragma unroll
    for (int off = 32; off > 0; off >>= 1) {
        a0 += __shfl_down(a0, off, 64);
        a1 += __shfl_down(a1, off, 64);
        a2 += __shfl_down(a2, off, 64);
        a3 += __shfl_down(a3, off, 64);
    }
    __shared__ float red[4][4];
    const int wid  = tid >> 6;
    const int lane = tid & 63;
    if (lane == 0) { red[wid][0]=a0; red[wid][1]=a1; red[wid][2]=a2; red[wid][3]=a3; }
    __syncthreads();
    if (tid == 0) {
        float r0 = red[0][0]+red[1][0]+red[2][0]+red[3][0]+embed_b[0];
        float r1 = red[0][1]+red[1][1]+red[2][1]+red[3][1]+embed_b[1];
        float r2 = red[0][2]+red[1][2]+red[2][2]+red[3][2]+embed_b[2];
        float r3 = red[0][3]+red[1][3]+red[2][3]+red[3][3]+embed_b[3];
        ((float4*)(embedded + (size_t)b * 4))[0] = make_float4(r0, r1, r2, r3);
    }
}

// ---------------------------------------------------------------------------
// Kernel 2: sum NSLICE partials (+bias) -> embedded, then q = e@rot, k = e@ent
// ---------------------------------------------------------------------------
__global__ __launch_bounds__(256) void qk_reduce_kernel(
    const float* __restrict__ partial, const float* __restrict__ embed_b,
    const float* __restrict__ rot, const float* __restrict__ ent,
    float* __restrict__ embedded, float* __restrict__ q, float* __restrict__ k)
{
    int b = blockIdx.x * 256 + threadIdx.x;
    if (b >= NB) return;
    float r0 = embed_b[0], r1 = embed_b[1], r2 = embed_b[2], r3 = embed_b[3];
    #pragma unroll
    for (int s = 0; s < NSLICE; ++s) {
        float4 p = ((const float4*)partial)[(size_t)s * NB + b];
        r0 += p.x; r1 += p.y; r2 += p.z; r3 += p.w;
    }
    float4 ev = make_float4(r0, r1, r2, r3);
    ((float4*)embedded)[b] = ev;
    float qv[4], kv[4];
    #pragma unroll
    for (int c = 0; c < 4; ++c) {
        qv[c] = ev.x * rot[0*4+c] + ev.y * rot[1*4+c] + ev.z * rot[2*4+c] + ev.w * rot[3*4+c];
        kv[c] = ev.x * ent[0*4+c] + ev.y * ent[1*4+c] + ev.z * ent[2*4+c] + ev.w * ent[3*4+c];
    }
    ((float4*)q)[b] = make_float4(qv[0], qv[1], qv[2], qv[3]);
    ((float4*)k)[b] = make_float4(kv[0], kv[1], kv[2], kv[3]);
}

// plain qk for the fallback path
__global__ __launch_bounds__(256) void qk_kernel(
    const float* __restrict__ embedded, const float* __restrict__ rot,
    const float* __restrict__ ent, float* __restrict__ q, float* __restrict__ k)
{
    int b = blockIdx.x * 256 + threadIdx.x;
    if (b >= NB) return;
    float4 ev = ((const float4*)embedded)[b];
    float qv[4], kv[4];
    #pragma unroll
    for (int c = 0; c < 4; ++c) {
        qv[c] = ev.x * rot[0*4+c] + ev.y * rot[1*4+c] + ev.z * rot[2*4+c] + ev.w * rot[3*4+c];
        kv[c] = ev.x * ent[0*4+c] + ev.y * ent[1*4+c] + ev.z * ent[2*4+c] + ev.w * ent[3*4+c];
    }
    ((float4*)q)[b] = make_float4(qv[0], qv[1], qv[2], qv[3]);
    ((float4*)k)[b] = make_float4(kv[0], kv[1], kv[2], kv[3]);
}

// ---------------------------------------------------------------------------
// Kernel 3: per-row softmax attention + mean + sigmoid -> out [NB, 2]
// ---------------------------------------------------------------------------
__global__ __launch_bounds__(256) void attn_kernel(
    const float* __restrict__ embedded, const float* __restrict__ q,
    const float* __restrict__ k, float* __restrict__ out)
{
    __shared__ float4 k_lds[NB];
    __shared__ float4 e_lds[NB];
    const int r   = blockIdx.x;
    const int tid = threadIdx.x;

    for (int c = tid; c < NB; c += 256) {
        k_lds[c] = ((const float4*)k)[c];
        e_lds[c] = ((const float4*)embedded)[c];
    }
    __syncthreads();

    const float4 qr = ((const float4*)q)[r];

    float m = -INFINITY, l = 0.f;
    float a0 = 0.f, a1 = 0.f, a2 = 0.f, a3 = 0.f;

    for (int c = tid; c < NB; c += 256) {
        float4 kc = k_lds[c];
        float s = 0.5f * (qr.x * kc.x + qr.y * kc.y + qr.z * kc.z + qr.w * kc.w);
        float mn    = fmaxf(m, s);
        float scale = __expf(m - mn);
        float p     = __expf(s - mn);
        float4 ec = e_lds[c];
        l  = l  * scale + p;
        a0 = a0 * scale + p * ec.x;
        a1 = a1 * scale + p * ec.y;
        a2 = a2 * scale + p * ec.z;
        a3 = a3 * scale + p * ec.w;
        m = mn;
    }

    #pragma unroll
    for (int off = 32; off > 0; off >>= 1) {
        float m2 = __shfl_down(m,  off, 64);
        float l2 = __shfl_down(l,  off, 64);
        float b0 = __shfl_down(a0, off, 64);
        float b1 = __shfl_down(a1, off, 64);
        float b2 = __shfl_down(a2, off, 64);
        float b3 = __shfl_down(a3, off, 64);
        float mn = fmaxf(m, m2);
        float s1 = __expf(m - mn), s2 = __expf(m2 - mn);
        l  = l  * s1 + l2 * s2;
        a0 = a0 * s1 + b0 * s2;
        a1 = a1 * s1 + b1 * s2;
        a2 = a2 * s1 + b2 * s2;
        a3 = a3 * s1 + b3 * s2;
        m = mn;
    }

    __shared__ float wred[4][6];
    const int wid  = tid >> 6;
    const int lane = tid & 63;
    if (lane == 0) {
        wred[wid][0] = m;  wred[wid][1] = l;
        wred[wid][2] = a0; wred[wid][3] = a1;
        wred[wid][4] = a2; wred[wid][5] = a3;
    }
    __syncthreads();
    if (tid == 0) {
        float M = wred[0][0], L = wred[0][1];
        float A0 = wred[0][2], A1 = wred[0][3], A2 = wred[0][4], A3 = wred[0][5];
        #pragma unroll
        for (int w = 1; w < 4; ++w) {
            float m2 = wred[w][0];
            float mn = fmaxf(M, m2);
            float s1 = __expf(M - mn), s2 = __expf(m2 - mn);
            L  = L  * s1 + wred[w][1] * s2;
            A0 = A0 * s1 + wred[w][2] * s2;
            A1 = A1 * s1 + wred[w][3] * s2;
            A2 = A2 * s1 + wred[w][4] * s2;
            A3 = A3 * s1 + wred[w][5] * s2;
            M = mn;
        }
        float mean = (A0 + A1 + A2 + A3) / (4.0f * L);
        float prob = 1.0f / (1.0f + __expf(-mean));
        out[r * 2 + 0] = prob;
        out[r * 2 + 1] = 1.0f - prob;
    }
}

// ---------------------------------------------------------------------------
extern "C" void kernel_launch(void* const* d_in, const int* in_sizes, int n_in,
                              void* d_out, int out_size, void* d_ws, size_t ws_size,
                              hipStream_t stream) {
    const float* x       = (const float*)d_in[0];
    const float* conv_w  = (const float*)d_in[1];
    const float* conv_b  = (const float*)d_in[2];
    const float* embed_w = (const float*)d_in[3];
    const float* embed_b = (const float*)d_in[4];
    const float* rot     = (const float*)d_in[5];
    const float* ent     = (const float*)d_in[6];
    float* out = (float*)d_out;

    float* partial  = (float*)d_ws;                 // NSLICE*NB*4 floats
    float* embedded = partial + NSLICE * NB * 4;    // NB*4
    float* q        = embedded + NB * 4;            // NB*4
    float* k        = q + NB * 4;                   // NB*4
    float* ew_pack  = k + NB * 4;                   // EWPK floats

    const size_t need = (size_t)(NSLICE * NB * 4 + NB * 12 + EWPK) * sizeof(float);

    if (ws_size >= need) {
        pack_ew_kernel<<<(NGRP * 4 + 255) / 256, 256, 0, stream>>>(embed_w, ew_pack);
        conv_embed_multi<<<ISETS * NSLICE, 256, 0, stream>>>(x, conv_w, conv_b,
                                                             ew_pack, partial);
        qk_reduce_kernel<<<NB / 256, 256, 0, stream>>>(partial, embed_b, rot, ent,
                                                       embedded, q, k);
    } else {
        conv_embed_kernel<<<NB, 256, 0, stream>>>(x, conv_w, conv_b, embed_w,
                                                  embed_b, embedded);
        qk_kernel<<<NB / 256, 256, 0, stream>>>(embedded, rot, ent, q, k);
    }
    attn_kernel<<<NB, 256, 0, stream>>>(embedded, q, k, out);
}

// Round 6
// 73.326 us; speedup vs baseline: 1.3591x; 1.0453x over previous
//
#include <hip/hip_runtime.h>
#include <math.h>

#define HW     224
#define IMG    (HW * HW)        // 50176
#define OW     223
#define FLAT   (OW * OW)        // 49729
#define NB     1024             // batch
#define NGRP   (OW * 56)        // 12488 groups of 4 positions
#define EWPK   (NGRP * 16)      // packed embed_w floats
#define NI     4                // images per block
#define NSLICE 8                // position slices
#define ISETS  (NB / NI)        // 256 image sets
#define FULLC  48               // full chunks (48*256 = 12288 groups)
#define TAILN  (NGRP - FULLC * 256)   // 200 tail groups (chunk 48, slice 0)

// ---------------------------------------------------------------------------
// Kernel 0: repack embed_w [4][FLAT] -> ew_pack[g][c][4]; zero-fill the
// invalid col-223 slot (the .w of group jg==55).
// ---------------------------------------------------------------------------
__global__ __launch_bounds__(256) void pack_ew_kernel(
    const float* __restrict__ embed_w, float* __restrict__ ew_pack)
{
    int idx = blockIdx.x * 256 + threadIdx.x;
    if (idx >= NGRP * 4) return;
    int g = idx >> 2;
    int c = idx & 3;
    int i  = g / 56;
    int j0 = (g - i * 56) * 4;
    const float* src = embed_w + (size_t)c * FLAT + (size_t)i * OW + j0;
    float v0 = src[0];
    float v1 = (j0 + 1 < OW) ? src[1] : 0.f;
    float v2 = (j0 + 2 < OW) ? src[2] : 0.f;
    float v3 = (j0 + 3 < OW) ? src[3] : 0.f;
    ((float4*)(ew_pack + (size_t)g * 16 + c * 4))[0] = make_float4(v0, v1, v2, v3);
}

// ---------------------------------------------------------------------------
// Batch of loads for one (chunk, thread): 4 ew float4 + per-image t/bt/te/be.
// All members are scalar fields -> stays in registers (no dynamic indexing).
// ---------------------------------------------------------------------------
struct Batch {
    float4 e0, e1, e2, e3;
    float4 t0, t1, t2, t3;
    float4 bb0, bb1, bb2, bb3;
    float  te0, te1, te2, te3;
    float  be0, be1, be2, be3;
};

__device__ __forceinline__ void load_batch(
    Batch& B, const float* __restrict__ xb0,
    const float* __restrict__ ew_pack, int g)
{
    const int i    = g / 56;
    const int jg   = g - i * 56;
    const int xoff = i * HW + jg * 4;
    const int beo  = (jg == 55) ? HW : HW + 4;   // clamp: never past allocation
    const float4* ep = (const float4*)(ew_pack + (size_t)g * 16);
    B.e0 = ep[0]; B.e1 = ep[1]; B.e2 = ep[2]; B.e3 = ep[3];
    const float* x0 = xb0 + xoff;
    const float* x1 = x0 + IMG;
    const float* x2 = x1 + IMG;
    const float* x3 = x2 + IMG;
    B.t0 = *(const float4*)x0; B.bb0 = *(const float4*)(x0 + HW);
    B.t1 = *(const float4*)x1; B.bb1 = *(const float4*)(x1 + HW);
    B.t2 = *(const float4*)x2; B.bb2 = *(const float4*)(x2 + HW);
    B.t3 = *(const float4*)x3; B.bb3 = *(const float4*)(x3 + HW);
    B.te0 = x0[4]; B.be0 = x0[beo];
    B.te1 = x1[4]; B.be1 = x1[beo];
    B.te2 = x2[4]; B.be2 = x2[beo];
    B.te3 = x3[4]; B.be3 = x3[beo];
}

#define COMP_ONE(T, BT, TE, BE, IM)                                             \
    {                                                                           \
        float z0 = w00 * B.T.x + w01 * B.T.y + w10 * B.BT.x + w11 * B.BT.y + cb;\
        float z1 = w00 * B.T.y + w01 * B.T.z + w10 * B.BT.y + w11 * B.BT.z + cb;\
        float z2 = w00 * B.T.z + w01 * B.T.w + w10 * B.BT.z + w11 * B.BT.w + cb;\
        float z3 = w00 * B.T.w + w01 * B.TE  + w10 * B.BT.w + w11 * B.BE  + cb; \
        float s0 = __builtin_amdgcn_rcpf(1.0f + __expf(-z0));                   \
        float s1 = __builtin_amdgcn_rcpf(1.0f + __expf(-z1));                   \
        float s2 = __builtin_amdgcn_rcpf(1.0f + __expf(-z2));                   \
        float s3 = __builtin_amdgcn_rcpf(1.0f + __expf(-z3));                   \
        acc[IM][0] += s0 * B.e0.x + s1 * B.e0.y + s2 * B.e0.z + s3 * B.e0.w;    \
        acc[IM][1] += s0 * B.e1.x + s1 * B.e1.y + s2 * B.e1.z + s3 * B.e1.w;    \
        acc[IM][2] += s0 * B.e2.x + s1 * B.e2.y + s2 * B.e2.z + s3 * B.e2.w;    \
        acc[IM][3] += s0 * B.e3.x + s1 * B.e3.y + s2 * B.e3.z + s3 * B.e3.w;    \
    }

// ---------------------------------------------------------------------------
// Kernel 1: fused conv+sigmoid+embed, 2-deep register pipeline.
// Block = (image set of 4, slice). Each slice runs exactly 6 branch-free
// chunks (fully unrolled); slice 0 additionally handles the 200-group tail.
// ---------------------------------------------------------------------------
__global__ __launch_bounds__(256, 3) void conv_embed_pipe(
    const float* __restrict__ x, const float* __restrict__ conv_w,
    const float* __restrict__ conv_b, const float* __restrict__ ew_pack,
    float* __restrict__ partial)   // [NSLICE][NB][4]
{
    const int blk   = blockIdx.x;
    const int slice = blk & (NSLICE - 1);
    const int b0    = (blk >> 3) * NI;
    const int tid   = threadIdx.x;

    const float w00 = conv_w[0], w01 = conv_w[1];
    const float w10 = conv_w[2], w11 = conv_w[3];
    const float cb  = conv_b[0];

    const float* __restrict__ xb0 = x + (size_t)b0 * IMG;

    float acc[NI][4];
    #pragma unroll
    for (int im = 0; im < NI; ++im)
        acc[im][0] = acc[im][1] = acc[im][2] = acc[im][3] = 0.f;

    // g for pipeline stage it: chunk (slice + it*NSLICE), all < 12288 -> valid
    Batch A, Bq;
    load_batch(A, xb0, ew_pack, slice * 256 + tid);

    #pragma unroll
    for (int it = 0; it < 6; ++it) {
        if (it + 1 < 6) {
            const int gn = (slice + (it + 1) * NSLICE) * 256 + tid;
            if ((it & 1) == 0) load_batch(Bq, xb0, ew_pack, gn);
            else               load_batch(A,  xb0, ew_pack, gn);
        }
        if ((it & 1) == 0) {
            Batch& B = A;
            COMP_ONE(t0, bb0, te0, be0, 0)
            COMP_ONE(t1, bb1, te1, be1, 1)
            COMP_ONE(t2, bb2, te2, be2, 2)
            COMP_ONE(t3, bb3, te3, be3, 3)
        } else {
            Batch& B = Bq;
            COMP_ONE(t0, bb0, te0, be0, 0)
            COMP_ONE(t1, bb1, te1, be1, 1)
            COMP_ONE(t2, bb2, te2, be2, 2)
            COMP_ONE(t3, bb3, te3, be3, 3)
        }
    }

    if (slice == 0 && tid < TAILN) {      // tail chunk 48: groups 12288..12487
        Batch T;
        load_batch(T, xb0, ew_pack, FULLC * 256 + tid);
        Batch& B = T;
        COMP_ONE(t0, bb0, te0, be0, 0)
        COMP_ONE(t1, bb1, te1, be1, 1)
        COMP_ONE(t2, bb2, te2, be2, 2)
        COMP_ONE(t3, bb3, te3, be3, 3)
    }

    // ---- wave reduction ----
    #pragma unroll
    for (int off = 32; off > 0; off >>= 1) {
        #pragma unroll
        for (int im = 0; im < NI; ++im) {
            acc[im][0] += __shfl_down(acc[im][0], off, 64);
            acc[im][1] += __shfl_down(acc[im][1], off, 64);
            acc[im][2] += __shfl_down(acc[im][2], off, 64);
            acc[im][3] += __shfl_down(acc[im][3], off, 64);
        }
    }

    __shared__ float red[4][NI][4];
    const int wid  = tid >> 6;
    const int lane = tid & 63;
    if (lane == 0) {
        #pragma unroll
        for (int im = 0; im < NI; ++im) {
            red[wid][im][0] = acc[im][0]; red[wid][im][1] = acc[im][1];
            red[wid][im][2] = acc[im][2]; red[wid][im][3] = acc[im][3];
        }
    }
    __syncthreads();
    if (tid < NI) {
        float r0 = red[0][tid][0] + red[1][tid][0] + red[2][tid][0] + red[3][tid][0];
        float r1 = red[0][tid][1] + red[1][tid][1] + red[2][tid][1] + red[3][tid][1];
        float r2 = red[0][tid][2] + red[1][tid][2] + red[2][tid][2] + red[3][tid][2];
        float r3 = red[0][tid][3] + red[1][tid][3] + red[2][tid][3] + red[3][tid][3];
        ((float4*)(partial + ((size_t)slice * NB + b0 + tid) * 4))[0] =
            make_float4(r0, r1, r2, r3);
    }
}

// ---------------------------------------------------------------------------
// Fallback (round-1 style) if ws too small.
// ---------------------------------------------------------------------------
__global__ __launch_bounds__(256) void conv_embed_kernel(
    const float* __restrict__ x, const float* __restrict__ conv_w,
    const float* __restrict__ conv_b, const float* __restrict__ embed_w,
    const float* __restrict__ embed_b, float* __restrict__ embedded)
{
    const int b   = blockIdx.x;
    const int tid = threadIdx.x;
    const float w00 = conv_w[0], w01 = conv_w[1];
    const float w10 = conv_w[2], w11 = conv_w[3];
    const float cb  = conv_b[0];
    const float* __restrict__ xb  = x + (size_t)b * IMG;
    const float* __restrict__ ew0 = embed_w;
    const float* __restrict__ ew1 = embed_w + FLAT;
    const float* __restrict__ ew2 = embed_w + 2 * FLAT;
    const float* __restrict__ ew3 = embed_w + 3 * FLAT;
    float a0 = 0.f, a1 = 0.f, a2 = 0.f, a3 = 0.f;
    for (int p = tid; p < FLAT; p += 256) {
        unsigned up = (unsigned)p;
        unsigned i  = up / 223u;
        unsigned j  = up - i * 223u;
        const float* xr = xb + i * HW + j;
        float z = w00 * xr[0] + w01 * xr[1] + w10 * xr[HW] + w11 * xr[HW + 1] + cb;
        float s = 1.0f / (1.0f + __expf(-z));
        a0 += s * ew0[p]; a1 += s * ew1[p]; a2 += s * ew2[p]; a3 += s * ew3[p];
    }
    #pragma unroll
    for (int off = 32; off > 0; off >>= 1) {
        a0 += __shfl_down(a0, off, 64);
        a1 += __shfl_down(a1, off, 64);
        a2 += __shfl_down(a2, off, 64);
        a3 += __shfl_down(a3, off, 64);
    }
    __shared__ float red[4][4];
    const int wid  = tid >> 6;
    const int lane = tid & 63;
    if (lane == 0) { red[wid][0]=a0; red[wid][1]=a1; red[wid][2]=a2; red[wid][3]=a3; }
    __syncthreads();
    if (tid == 0) {
        float r0 = red[0][0]+red[1][0]+red[2][0]+red[3][0]+embed_b[0];
        float r1 = red[0][1]+red[1][1]+red[2][1]+red[3][1]+embed_b[1];
        float r2 = red[0][2]+red[1][2]+red[2][2]+red[3][2]+embed_b[2];
        float r3 = red[0][3]+red[1][3]+red[2][3]+red[3][3]+embed_b[3];
        ((float4*)(embedded + (size_t)b * 4))[0] = make_float4(r0, r1, r2, r3);
    }
}

// ---------------------------------------------------------------------------
// Kernel 2: sum NSLICE partials (+bias) -> embedded, then q/k projections
// ---------------------------------------------------------------------------
__global__ __launch_bounds__(256) void qk_reduce_kernel(
    const float* __restrict__ partial, const float* __restrict__ embed_b,
    const float* __restrict__ rot, const float* __restrict__ ent,
    float* __restrict__ embedded, float* __restrict__ q, float* __restrict__ k)
{
    int b = blockIdx.x * 256 + threadIdx.x;
    if (b >= NB) return;
    float r0 = embed_b[0], r1 = embed_b[1], r2 = embed_b[2], r3 = embed_b[3];
    #pragma unroll
    for (int s = 0; s < NSLICE; ++s) {
        float4 p = ((const float4*)partial)[(size_t)s * NB + b];
        r0 += p.x; r1 += p.y; r2 += p.z; r3 += p.w;
    }
    float4 ev = make_float4(r0, r1, r2, r3);
    ((float4*)embedded)[b] = ev;
    float qv[4], kv[4];
    #pragma unroll
    for (int c = 0; c < 4; ++c) {
        qv[c] = ev.x * rot[0*4+c] + ev.y * rot[1*4+c] + ev.z * rot[2*4+c] + ev.w * rot[3*4+c];
        kv[c] = ev.x * ent[0*4+c] + ev.y * ent[1*4+c] + ev.z * ent[2*4+c] + ev.w * ent[3*4+c];
    }
    ((float4*)q)[b] = make_float4(qv[0], qv[1], qv[2], qv[3]);
    ((float4*)k)[b] = make_float4(kv[0], kv[1], kv[2], kv[3]);
}

__global__ __launch_bounds__(256) void qk_kernel(
    const float* __restrict__ embedded, const float* __restrict__ rot,
    const float* __restrict__ ent, float* __restrict__ q, float* __restrict__ k)
{
    int b = blockIdx.x * 256 + threadIdx.x;
    if (b >= NB) return;
    float4 ev = ((const float4*)embedded)[b];
    float qv[4], kv[4];
    #pragma unroll
    for (int c = 0; c < 4; ++c) {
        qv[c] = ev.x * rot[0*4+c] + ev.y * rot[1*4+c] + ev.z * rot[2*4+c] + ev.w * rot[3*4+c];
        kv[c] = ev.x * ent[0*4+c] + ev.y * ent[1*4+c] + ev.z * ent[2*4+c] + ev.w * ent[3*4+c];
    }
    ((float4*)q)[b] = make_float4(qv[0], qv[1], qv[2], qv[3]);
    ((float4*)k)[b] = make_float4(kv[0], kv[1], kv[2], kv[3]);
}

// ---------------------------------------------------------------------------
// Kernel 3: per-row softmax attention + mean + sigmoid -> out [NB, 2]
// ---------------------------------------------------------------------------
__global__ __launch_bounds__(256) void attn_kernel(
    const float* __restrict__ embedded, const float* __restrict__ q,
    const float* __restrict__ k, float* __restrict__ out)
{
    __shared__ float4 k_lds[NB];
    __shared__ float4 e_lds[NB];
    const int r   = blockIdx.x;
    const int tid = threadIdx.x;

    for (int c = tid; c < NB; c += 256) {
        k_lds[c] = ((const float4*)k)[c];
        e_lds[c] = ((const float4*)embedded)[c];
    }
    __syncthreads();

    const float4 qr = ((const float4*)q)[r];

    float m = -INFINITY, l = 0.f;
    float a0 = 0.f, a1 = 0.f, a2 = 0.f, a3 = 0.f;

    for (int c = tid; c < NB; c += 256) {
        float4 kc = k_lds[c];
        float s = 0.5f * (qr.x * kc.x + qr.y * kc.y + qr.z * kc.z + qr.w * kc.w);
        float mn    = fmaxf(m, s);
        float scale = __expf(m - mn);
        float p     = __expf(s - mn);
        float4 ec = e_lds[c];
        l  = l  * scale + p;
        a0 = a0 * scale + p * ec.x;
        a1 = a1 * scale + p * ec.y;
        a2 = a2 * scale + p * ec.z;
        a3 = a3 * scale + p * ec.w;
        m = mn;
    }

    #pragma unroll
    for (int off = 32; off > 0; off >>= 1) {
        float m2 = __shfl_down(m,  off, 64);
        float l2 = __shfl_down(l,  off, 64);
        float b0 = __shfl_down(a0, off, 64);
        float b1 = __shfl_down(a1, off, 64);
        float b2 = __shfl_down(a2, off, 64);
        float b3 = __shfl_down(a3, off, 64);
        float mn = fmaxf(m, m2);
        float s1 = __expf(m - mn), s2 = __expf(m2 - mn);
        l  = l  * s1 + l2 * s2;
        a0 = a0 * s1 + b0 * s2;
        a1 = a1 * s1 + b1 * s2;
        a2 = a2 * s1 + b2 * s2;
        a3 = a3 * s1 + b3 * s2;
        m = mn;
    }

    __shared__ float wred[4][6];
    const int wid  = tid >> 6;
    const int lane = tid & 63;
    if (lane == 0) {
        wred[wid][0] = m;  wred[wid][1] = l;
        wred[wid][2] = a0; wred[wid][3] = a1;
        wred[wid][4] = a2; wred[wid][5] = a3;
    }
    __syncthreads();
    if (tid == 0) {
        float M = wred[0][0], L = wred[0][1];
        float A0 = wred[0][2], A1 = wred[0][3], A2 = wred[0][4], A3 = wred[0][5];
        #pragma unroll
        for (int w = 1; w < 4; ++w) {
            float m2 = wred[w][0];
            float mn = fmaxf(M, m2);
            float s1 = __expf(M - mn), s2 = __expf(m2 - mn);
            L  = L  * s1 + wred[w][1] * s2;
            A0 = A0 * s1 + wred[w][2] * s2;
            A1 = A1 * s1 + wred[w][3] * s2;
            A2 = A2 * s1 + wred[w][4] * s2;
            A3 = A3 * s1 + wred[w][5] * s2;
            M = mn;
        }
        float mean = (A0 + A1 + A2 + A3) / (4.0f * L);
        float prob = 1.0f / (1.0f + __expf(-mean));
        out[r * 2 + 0] = prob;
        out[r * 2 + 1] = 1.0f - prob;
    }
}

// ---------------------------------------------------------------------------
extern "C" void kernel_launch(void* const* d_in, const int* in_sizes, int n_in,
                              void* d_out, int out_size, void* d_ws, size_t ws_size,
                              hipStream_t stream) {
    const float* x       = (const float*)d_in[0];
    const float* conv_w  = (const float*)d_in[1];
    const float* conv_b  = (const float*)d_in[2];
    const float* embed_w = (const float*)d_in[3];
    const float* embed_b = (const float*)d_in[4];
    const float* rot     = (const float*)d_in[5];
    const float* ent     = (const float*)d_in[6];
    float* out = (float*)d_out;

    float* partial  = (float*)d_ws;                 // NSLICE*NB*4 floats
    float* embedded = partial + NSLICE * NB * 4;    // NB*4
    float* q        = embedded + NB * 4;            // NB*4
    float* k        = q + NB * 4;                   // NB*4
    float* ew_pack  = k + NB * 4;                   // EWPK floats

    const size_t need = (size_t)(NSLICE * NB * 4 + NB * 12 + EWPK) * sizeof(float);

    if (ws_size >= need) {
        pack_ew_kernel<<<(NGRP * 4 + 255) / 256, 256, 0, stream>>>(embed_w, ew_pack);
        conv_embed_pipe<<<ISETS * NSLICE, 256, 0, stream>>>(x, conv_w, conv_b,
                                                            ew_pack, partial);
        qk_reduce_kernel<<<NB / 256, 256, 0, stream>>>(partial, embed_b, rot, ent,
                                                       embedded, q, k);
    } else {
        conv_embed_kernel<<<NB, 256, 0, stream>>>(x, conv_w, conv_b, embed_w,
                                                  embed_b, embedded);
        qk_kernel<<<NB / 256, 256, 0, stream>>>(embedded, rot, ent, q, k);
    }
    attn_kernel<<<NB, 256, 0, stream>>>(embedded, q, k, out);
}